// Round 1
// baseline (414.460 us; speedup 1.0000x reference)
//
#include <hip/hip_runtime.h>
#include <math.h>

// Shapes: B=1, N=256, C=128, H=4, CH=32
// d_in order: act, mask, ln_g, ln_b, wq, wk, wv, w2d, wg, bg, wo, bo (all fp32)

#define NRES 256
#define CDIM 128

__device__ __forceinline__ float wave_reduce_sum(float v) {
  #pragma unroll
  for (int off = 32; off; off >>= 1) v += __shfl_xor(v, off, 64);
  return v;
}

// ---------------- Kernel 1: LayerNorm (with axis swap) + pair-bias dot ----------------
// lnx[mm][ii][c] = LN(act[0][ii][mm][:])[c]
// bias2[h][mm][ii] = dot(lnx[mm][ii][:], w2d[:,h])
__global__ __launch_bounds__(256) void k_ln(const float* __restrict__ act,
                                            const float* __restrict__ ln_g,
                                            const float* __restrict__ ln_b,
                                            const float* __restrict__ w2d,
                                            float* __restrict__ lnx,
                                            float* __restrict__ bias2) {
  int row  = blockIdx.x * 4 + (threadIdx.x >> 6);   // row = mm*256 + ii
  int lane = threadIdx.x & 63;
  int mm = row >> 8, ii = row & 255;
  const float* a = act + ((size_t)(ii * NRES + mm)) * CDIM;
  float a0 = a[lane], a1 = a[lane + 64];
  float sum = wave_reduce_sum(a0 + a1);
  float mean = sum * (1.f / 128.f);
  float e0 = a0 - mean, e1 = a1 - mean;
  float var = wave_reduce_sum(e0 * e0 + e1 * e1) * (1.f / 128.f);
  float rstd = rsqrtf(var + 1e-5f);
  float y0 = e0 * rstd * ln_g[lane]      + ln_b[lane];
  float y1 = e1 * rstd * ln_g[lane + 64] + ln_b[lane + 64];
  float* o = lnx + (size_t)row * CDIM;
  o[lane] = y0;
  o[lane + 64] = y1;
  #pragma unroll
  for (int h = 0; h < 4; ++h) {
    float b = y0 * w2d[lane * 4 + h] + y1 * w2d[(lane + 64) * 4 + h];
    b = wave_reduce_sum(b);
    if (lane == 0) bias2[h * 65536 + row] = b;
  }
}

// ---------------- Kernel 2: projections GEMM ----------------
// [65536 x 128] @ [128 x 128] for each of wq,wk,wv,wg.
// Output layout: dst[((m*4+h)*256 + i)*32 + ch].  q *= 1/sqrt(32); g += bg.
__global__ __launch_bounds__(256) void k_proj(const float* __restrict__ lnx,
                                              const float* __restrict__ wq,
                                              const float* __restrict__ wk,
                                              const float* __restrict__ wv,
                                              const float* __restrict__ wg,
                                              const float* __restrict__ bg,
                                              float* __restrict__ qb,
                                              float* __restrict__ kb,
                                              float* __restrict__ vb,
                                              float* __restrict__ gb) {
  __shared__ float As[16][68];
  __shared__ float Bs[16][68];
  int t = threadIdx.x;
  int row0 = blockIdx.x * 64;
  int cb = blockIdx.y;            // 0..7
  int which = cb >> 1;            // 0=q 1=k 2=v 3=g
  int hc0 = (cb & 1) * 64;
  const float* wsel = which == 0 ? wq : which == 1 ? wk : which == 2 ? wv : wg;
  float acc[4][4] = {};
  int tr = t >> 4, tc = t & 15;
  for (int kk = 0; kk < 128; kk += 16) {
    __syncthreads();
    {
      int r = t >> 2, j4 = t & 3;
      const float4 av = *(const float4*)(lnx + (size_t)(row0 + r) * 128 + kk + j4 * 4);
      As[j4 * 4 + 0][r] = av.x;
      As[j4 * 4 + 1][r] = av.y;
      As[j4 * 4 + 2][r] = av.z;
      As[j4 * 4 + 3][r] = av.w;
      int krow = t >> 4, c4 = t & 15;
      *(float4*)&Bs[krow][c4 * 4] = *(const float4*)(wsel + (size_t)(kk + krow) * 128 + hc0 + c4 * 4);
    }
    __syncthreads();
    #pragma unroll
    for (int j = 0; j < 16; ++j) {
      float4 a4 = *(const float4*)&As[j][tr * 4];
      float4 b4 = *(const float4*)&Bs[j][tc * 4];
      float av[4] = {a4.x, a4.y, a4.z, a4.w};
      float bv[4] = {b4.x, b4.y, b4.z, b4.w};
      #pragma unroll
      for (int x = 0; x < 4; ++x)
        #pragma unroll
        for (int y = 0; y < 4; ++y) acc[x][y] += av[x] * bv[y];
    }
  }
  float* dst = which == 0 ? qb : which == 1 ? kb : which == 2 ? vb : gb;
  const float factor = 0.17677669529663687f;  // 1/sqrt(32)
  #pragma unroll
  for (int x = 0; x < 4; ++x) {
    int r = row0 + tr * 4 + x;
    int m = r >> 8, i = r & 255;
    #pragma unroll
    for (int y = 0; y < 4; ++y) {
      int hc = hc0 + tc * 4 + y;
      float val = acc[x][y];
      if (which == 0) val *= factor;
      if (which == 3) val += bg[hc];
      int h = hc >> 5, ch = hc & 31;
      dst[(size_t)((m * 4 + h) * 256 + i) * 32 + ch] = val;
    }
  }
}

// ---------------- Kernel 3: attention per (m,h), flash-style ----------------
// logits[i][j] = q[m,i,h,:].k[m,j,h,:] + 1e9*(mask[j][m]-1) + bias2[h][i][j]
// out = softmax_j(logits) @ V, gated by sigmoid(g), stored [i][m][h*32+ch]
__global__ __launch_bounds__(256) void k_attn(const float* __restrict__ qb,
                                              const float* __restrict__ kb,
                                              const float* __restrict__ vb,
                                              const float* __restrict__ gb,
                                              const float* __restrict__ bias2,
                                              const float* __restrict__ mask,
                                              float* __restrict__ ao) {
  int m = blockIdx.x, h = blockIdx.y;
  int i = threadIdx.x;  // one attention row per thread
  __shared__ float Kc[32][36];
  __shared__ float Vc[32][36];
  __shared__ float maskb[256];
  maskb[i] = 1e9f * (mask[i * 256 + m] - 1.0f);
  const float* qrow = qb + (size_t)((m * 4 + h) * 256 + i) * 32;
  float qv[32];
  #pragma unroll
  for (int r = 0; r < 8; ++r) {
    float4 f = *(const float4*)(qrow + r * 4);
    qv[r * 4 + 0] = f.x; qv[r * 4 + 1] = f.y; qv[r * 4 + 2] = f.z; qv[r * 4 + 3] = f.w;
  }
  float acc[32] = {};
  float mx = -1e30f, l = 0.f;
  const float* b2row = bias2 + h * 65536 + i * 256;
  const size_t kvbase = (size_t)((m * 4 + h) * 256) * 32;
  for (int jc = 0; jc < 8; ++jc) {
    __syncthreads();
    {
      int j = i >> 3, c4 = i & 7;
      *(float4*)&Kc[j][c4 * 4] = *(const float4*)(kb + kvbase + (size_t)(jc * 32 + j) * 32 + c4 * 4);
      *(float4*)&Vc[j][c4 * 4] = *(const float4*)(vb + kvbase + (size_t)(jc * 32 + j) * 32 + c4 * 4);
    }
    __syncthreads();
    for (int jg = 0; jg < 4; ++jg) {
      float s8[8];
      float4 ba = *(const float4*)(b2row + jc * 32 + jg * 8);
      float4 bb = *(const float4*)(b2row + jc * 32 + jg * 8 + 4);
      float badd[8] = {ba.x, ba.y, ba.z, ba.w, bb.x, bb.y, bb.z, bb.w};
      #pragma unroll
      for (int jj = 0; jj < 8; ++jj) {
        int j = jg * 8 + jj;
        float s = 0.f;
        #pragma unroll
        for (int c4 = 0; c4 < 8; ++c4) {
          float4 kf = *(const float4*)&Kc[j][c4 * 4];
          s += qv[c4 * 4 + 0] * kf.x + qv[c4 * 4 + 1] * kf.y +
               qv[c4 * 4 + 2] * kf.z + qv[c4 * 4 + 3] * kf.w;
        }
        s8[jj] = s + maskb[jc * 32 + j] + badd[jj];
      }
      float gm = s8[0];
      #pragma unroll
      for (int jj = 1; jj < 8; ++jj) gm = fmaxf(gm, s8[jj]);
      float newm = fmaxf(mx, gm);
      float scale = __expf(mx - newm);
      l *= scale;
      #pragma unroll
      for (int c = 0; c < 32; ++c) acc[c] *= scale;
      mx = newm;
      #pragma unroll
      for (int jj = 0; jj < 8; ++jj) {
        int j = jg * 8 + jj;
        float p = __expf(s8[jj] - mx);
        l += p;
        #pragma unroll
        for (int c4 = 0; c4 < 8; ++c4) {
          float4 vf = *(const float4*)&Vc[j][c4 * 4];
          acc[c4 * 4 + 0] += p * vf.x;
          acc[c4 * 4 + 1] += p * vf.y;
          acc[c4 * 4 + 2] += p * vf.z;
          acc[c4 * 4 + 3] += p * vf.w;
        }
      }
    }
  }
  float invl = 1.f / l;
  const float* grow = gb + (size_t)((m * 4 + h) * 256 + i) * 32;
  float* orow = ao + (size_t)(i * 256 + m) * 128 + h * 32;
  #pragma unroll
  for (int c4 = 0; c4 < 8; ++c4) {
    float4 gf = *(const float4*)(grow + c4 * 4);
    float4 o;
    o.x = acc[c4 * 4 + 0] * invl * (1.f / (1.f + __expf(-gf.x)));
    o.y = acc[c4 * 4 + 1] * invl * (1.f / (1.f + __expf(-gf.y)));
    o.z = acc[c4 * 4 + 2] * invl * (1.f / (1.f + __expf(-gf.z)));
    o.w = acc[c4 * 4 + 3] * invl * (1.f / (1.f + __expf(-gf.w)));
    *(float4*)(orow + c4 * 4) = o;
  }
}

// ---------------- Kernel 4: output projection ----------------
// out[row][c] = attn_out[row][:] @ wo[:,c] + bo[c]   (row = ii*256+m already swapped)
__global__ __launch_bounds__(256) void k_out(const float* __restrict__ ao,
                                             const float* __restrict__ wo,
                                             const float* __restrict__ bo,
                                             float* __restrict__ out) {
  __shared__ float As[16][68];
  __shared__ float Bs[16][68];
  int t = threadIdx.x;
  int row0 = blockIdx.x * 64;
  int c0 = blockIdx.y * 64;
  float acc[4][4] = {};
  int tr = t >> 4, tc = t & 15;
  for (int kk = 0; kk < 128; kk += 16) {
    __syncthreads();
    {
      int r = t >> 2, j4 = t & 3;
      const float4 av = *(const float4*)(ao + (size_t)(row0 + r) * 128 + kk + j4 * 4);
      As[j4 * 4 + 0][r] = av.x;
      As[j4 * 4 + 1][r] = av.y;
      As[j4 * 4 + 2][r] = av.z;
      As[j4 * 4 + 3][r] = av.w;
      int krow = t >> 4, c4 = t & 15;
      *(float4*)&Bs[krow][c4 * 4] = *(const float4*)(wo + (size_t)(kk + krow) * 128 + c0 + c4 * 4);
    }
    __syncthreads();
    #pragma unroll
    for (int j = 0; j < 16; ++j) {
      float4 a4 = *(const float4*)&As[j][tr * 4];
      float4 b4 = *(const float4*)&Bs[j][tc * 4];
      float av[4] = {a4.x, a4.y, a4.z, a4.w};
      float bv[4] = {b4.x, b4.y, b4.z, b4.w};
      #pragma unroll
      for (int x = 0; x < 4; ++x)
        #pragma unroll
        for (int y = 0; y < 4; ++y) acc[x][y] += av[x] * bv[y];
    }
  }
  #pragma unroll
  for (int x = 0; x < 4; ++x) {
    int r = row0 + tr * 4 + x;
    float4 o;
    o.x = acc[x][0] + bo[c0 + tc * 4 + 0];
    o.y = acc[x][1] + bo[c0 + tc * 4 + 1];
    o.z = acc[x][2] + bo[c0 + tc * 4 + 2];
    o.w = acc[x][3] + bo[c0 + tc * 4 + 3];
    *(float4*)(out + (size_t)r * 128 + c0 + tc * 4) = o;
  }
}

extern "C" void kernel_launch(void* const* d_in, const int* in_sizes, int n_in,
                              void* d_out, int out_size, void* d_ws, size_t ws_size,
                              hipStream_t stream) {
  const float* act  = (const float*)d_in[0];
  const float* mask = (const float*)d_in[1];
  const float* ln_g = (const float*)d_in[2];
  const float* ln_b = (const float*)d_in[3];
  const float* wq   = (const float*)d_in[4];
  const float* wk   = (const float*)d_in[5];
  const float* wv   = (const float*)d_in[6];
  const float* w2d  = (const float*)d_in[7];
  const float* wg   = (const float*)d_in[8];
  const float* bg   = (const float*)d_in[9];
  const float* wo   = (const float*)d_in[10];
  const float* bo   = (const float*)d_in[11];

  float* W = (float*)d_ws;
  float* lnx   = W;                  // 8,388,608 floats
  float* bias2 = W + 8388608;        //   262,144 floats
  float* qb    = W + 8650752;        // 8,388,608
  float* kb    = W + 17039360;       // 8,388,608
  float* vb    = W + 25427968;       // 8,388,608
  float* gb    = W + 33816576;       // 8,388,608  (end = 42,205,184 floats = 161 MB)
  float* ao    = W;                  // reuse lnx region (dead after k_proj)
  float* out   = (float*)d_out;

  hipLaunchKernelGGL(k_ln,   dim3(16384),    dim3(256), 0, stream, act, ln_g, ln_b, w2d, lnx, bias2);
  hipLaunchKernelGGL(k_proj, dim3(1024, 8),  dim3(256), 0, stream, lnx, wq, wk, wv, wg, bg, qb, kb, vb, gb);
  hipLaunchKernelGGL(k_attn, dim3(256, 4),   dim3(256), 0, stream, qb, kb, vb, gb, bias2, mask, ao);
  hipLaunchKernelGGL(k_out,  dim3(1024, 2),  dim3(256), 0, stream, ao, wo, bo, out);
}

// Round 4
// 157.313 us; speedup vs baseline: 2.6346x; 2.6346x over previous
//
#include <hip/hip_runtime.h>
#include <hip/hip_bf16.h>
#include <math.h>

// Shapes: B=1, N=256, C=128, H=4, CH=32
// d_in order: act, mask, ln_g, ln_b, wq, wk, wv, w2d, wg, bg, wo, bo (all fp32)

typedef __attribute__((ext_vector_type(8))) short short8;   // 8 bf16 (4 VGPRs)
typedef __attribute__((ext_vector_type(4))) short short4v;  // 4 bf16 (2 VGPRs)
typedef __attribute__((ext_vector_type(4))) float f32x4;

__device__ __forceinline__ unsigned short f2bf(float f) {
  __hip_bfloat16 b = __float2bfloat16(f);
  return __builtin_bit_cast(unsigned short, b);
}

__device__ __forceinline__ f32x4 mfma16(short8 a, short8 b, f32x4 c) {
  return __builtin_amdgcn_mfma_f32_16x16x32_bf16(a, b, c, 0, 0, 0);
}

__device__ __forceinline__ float wave_reduce_sum(float v) {
  #pragma unroll
  for (int off = 32; off; off >>= 1) v += __shfl_xor(v, off, 64);
  return v;
}

// ---------------- K0: convert weights to bf16, transposed ----------------
__global__ __launch_bounds__(256) void k_conv(const float* __restrict__ wq,
                                              const float* __restrict__ wk,
                                              const float* __restrict__ wv,
                                              const float* __restrict__ wg,
                                              const float* __restrict__ wo,
                                              unsigned short* __restrict__ Wt4,
                                              unsigned short* __restrict__ Wto) {
  int idx = blockIdx.x * 256 + threadIdx.x;
  if (idx < 65536) {
    int n = idx >> 7, k = idx & 127;
    const float* ws = (n < 128) ? wq : (n < 256) ? wk : (n < 384) ? wv : wg;
    Wt4[idx] = f2bf(ws[k * 128 + (n & 127)]);
  } else if (idx < 81920) {
    int j = idx - 65536;
    int n = j >> 7, k = j & 127;
    Wto[j] = f2bf(wo[k * 128 + n]);
  }
}

// ---------------- K1: LayerNorm (axis-swapped) + pair-bias dot ----------------
__global__ __launch_bounds__(256) void k_ln(const float* __restrict__ act,
                                            const float* __restrict__ ln_g,
                                            const float* __restrict__ ln_b,
                                            const float* __restrict__ w2d,
                                            unsigned short* __restrict__ lnxb,
                                            float* __restrict__ bias2) {
  int row  = blockIdx.x * 4 + (threadIdx.x >> 6);
  int lane = threadIdx.x & 63;
  int mm = row >> 8, ii = row & 255;
  const float* a = act + ((size_t)(ii * 256 + mm)) * 128;
  float a0 = a[lane], a1 = a[lane + 64];
  float sum = wave_reduce_sum(a0 + a1);
  float mean = sum * (1.f / 128.f);
  float e0 = a0 - mean, e1 = a1 - mean;
  float var = wave_reduce_sum(e0 * e0 + e1 * e1) * (1.f / 128.f);
  float rstd = rsqrtf(var + 1e-5f);
  float y0 = e0 * rstd * ln_g[lane]      + ln_b[lane];
  float y1 = e1 * rstd * ln_g[lane + 64] + ln_b[lane + 64];
  unsigned short* o = lnxb + (size_t)row * 128;
  o[lane]      = f2bf(y0);
  o[lane + 64] = f2bf(y1);
  #pragma unroll
  for (int h = 0; h < 4; ++h) {
    float b = y0 * w2d[lane * 4 + h] + y1 * w2d[(lane + 64) * 4 + h];
    b = wave_reduce_sum(b);
    if (lane == 0) bias2[h * 65536 + row] = b;
  }
}

// ---------------- K2: fused q/k/v/g projection, bf16 MFMA ----------------
__global__ __launch_bounds__(256) void k_projg(const unsigned short* __restrict__ A,
                                               const unsigned short* __restrict__ Bt,
                                               const float* __restrict__ bg,
                                               unsigned short* __restrict__ qb,
                                               unsigned short* __restrict__ kb,
                                               unsigned short* __restrict__ vb,
                                               float* __restrict__ sgb) {
  __shared__ unsigned short As[128 * 40];
  __shared__ unsigned short Bs[64 * 40];
  int t = threadIdx.x;
  int m0 = blockIdx.x * 128, n0 = blockIdx.y * 64;
  int w = t >> 6, l = t & 63, g = l >> 4, li = l & 15;
  int wr = w >> 1, wc = w & 1;
  f32x4 acc[4][2] = {};
  for (int s = 0; s < 4; ++s) {
    int k0 = s * 32;
    __syncthreads();
    {
      int row = t >> 1, kl = (t & 1) * 16;
      const short8* src = (const short8*)(A + (size_t)(m0 + row) * 128 + k0 + kl);
      *(short8*)&As[row * 40 + kl]     = src[0];
      *(short8*)&As[row * 40 + kl + 8] = src[1];
      int bn = t >> 2, bk = (t & 3) * 8;
      *(short8*)&Bs[bn * 40 + bk] = *(const short8*)(Bt + (size_t)(n0 + bn) * 128 + k0 + bk);
    }
    __syncthreads();
    short8 af[4], bf[2];
    #pragma unroll
    for (int it = 0; it < 4; ++it)
      af[it] = *(const short8*)&As[(wr * 64 + it * 16 + li) * 40 + g * 8];
    #pragma unroll
    for (int jt = 0; jt < 2; ++jt)
      bf[jt] = *(const short8*)&Bs[(wc * 32 + jt * 16 + li) * 40 + g * 8];
    #pragma unroll
    for (int it = 0; it < 4; ++it)
      #pragma unroll
      for (int jt = 0; jt < 2; ++jt)
        acc[it][jt] = mfma16(af[it], bf[jt], acc[it][jt]);
  }
  int which = n0 >> 7;
  const float factor = 0.17677669529663687f;  // 1/sqrt(32)
  #pragma unroll
  for (int it = 0; it < 4; ++it)
    #pragma unroll
    for (int jt = 0; jt < 2; ++jt) {
      int n = n0 + wc * 32 + jt * 16 + li;
      int hh = (n >> 5) & 3, ch = n & 31;
      #pragma unroll
      for (int r = 0; r < 4; ++r) {
        int R = m0 + wr * 64 + it * 16 + g * 4 + r;
        int mm = R >> 8, ii = R & 255;
        size_t o = ((size_t)((mm * 4 + hh) * 256 + ii)) * 32 + ch;
        float v = acc[it][jt][r];
        if (which == 0)      qb[o] = f2bf(v * factor);
        else if (which == 1) kb[o] = f2bf(v);
        else if (which == 2) vb[o] = f2bf(v);
        else                 sgb[o] = 1.f / (1.f + __expf(-(v + bg[n & 127])));
      }
    }
}

// ---------------- K3: attention per (m,h), MFMA flash-style ----------------
__global__ __launch_bounds__(256) void k_attn(const unsigned short* __restrict__ qb,
                                              const unsigned short* __restrict__ kb,
                                              const unsigned short* __restrict__ vb,
                                              const float* __restrict__ sgb,
                                              const float* __restrict__ bias2,
                                              const float* __restrict__ mask,
                                              unsigned short* __restrict__ aob) {
  __shared__ unsigned short VT[32 * 264];    // V^T [c][j], pad 264 (528B stride)
  __shared__ unsigned short Pl[4 * 64 * 72]; // per-wave P [i][j], pad 72 (144B)
  __shared__ float maskls[256];
  int m = blockIdx.x, h = blockIdx.y;
  int t = threadIdx.x, w = t >> 6, l = t & 63, g = l >> 4, li = l & 15;
  int base = (m * 4 + h) << 8;
  maskls[t] = 1e9f * (mask[t * 256 + m] - 1.0f);
  {  // stage V^T
    const unsigned int* v32 = (const unsigned int*)(vb + (size_t)base * 32);
    #pragma unroll
    for (int p = 0; p < 16; ++p) {
      int idx = t + p * 256;
      int j = idx >> 4, cp = idx & 15;
      unsigned int u = v32[j * 16 + cp];
      VT[(cp * 2) * 264 + j]     = (unsigned short)(u & 0xffff);
      VT[(cp * 2 + 1) * 264 + j] = (unsigned short)(u >> 16);
    }
  }
  __syncthreads();
  short8 qf[4];
  #pragma unroll
  for (int it = 0; it < 4; ++it)
    qf[it] = *(const short8*)(qb + ((size_t)(base + w * 64 + it * 16 + li)) * 32 + g * 8);
  float mst[4] = {-1e30f, -1e30f, -1e30f, -1e30f};
  float lst[4] = {0.f, 0.f, 0.f, 0.f};
  f32x4 oacc[2][4] = {};
  const float* b2 = bias2 + (size_t)h * 65536;
  unsigned short* Pw = Pl + w * 64 * 72;
  for (int jc = 0; jc < 4; ++jc) {
    int j0 = jc * 64;
    f32x4 sacc[4][4];
    #pragma unroll
    for (int jt = 0; jt < 4; ++jt) {
      short8 kf = *(const short8*)(kb + ((size_t)(base + j0 + jt * 16 + li)) * 32 + g * 8);
      #pragma unroll
      for (int it = 0; it < 4; ++it) {
        f32x4 z = {0.f, 0.f, 0.f, 0.f};
        sacc[jt][it] = mfma16(kf, qf[it], z);
      }
    }
    #pragma unroll
    for (int it = 0; it < 4; ++it) {
      int ic = w * 64 + it * 16 + li;
      float s[16];
      float cmax = -1e30f;
      #pragma unroll
      for (int jt = 0; jt < 4; ++jt) {
        f32x4 bv = *(const f32x4*)(b2 + (size_t)ic * 256 + j0 + jt * 16 + g * 4);
        f32x4 mk = *(const f32x4*)&maskls[j0 + jt * 16 + g * 4];
        #pragma unroll
        for (int r = 0; r < 4; ++r) {
          float sv = sacc[jt][it][r] + bv[r] + mk[r];
          s[jt * 4 + r] = sv;
          cmax = fmaxf(cmax, sv);
        }
      }
      cmax = fmaxf(cmax, __shfl_xor(cmax, 16));
      cmax = fmaxf(cmax, __shfl_xor(cmax, 32));
      float mnew = fmaxf(mst[it], cmax);
      float fac = __expf(mst[it] - mnew);
      mst[it] = mnew;
      lst[it] *= fac;
      oacc[0][it] *= fac;
      oacc[1][it] *= fac;
      float psum = 0.f;
      #pragma unroll
      for (int jt = 0; jt < 4; ++jt) {
        float p0 = __expf(s[jt * 4 + 0] - mnew);
        float p1 = __expf(s[jt * 4 + 1] - mnew);
        float p2 = __expf(s[jt * 4 + 2] - mnew);
        float p3 = __expf(s[jt * 4 + 3] - mnew);
        psum += p0 + p1 + p2 + p3;
        short4v pk;
        pk.x = (short)f2bf(p0); pk.y = (short)f2bf(p1);
        pk.z = (short)f2bf(p2); pk.w = (short)f2bf(p3);
        *(short4v*)&Pw[(it * 16 + li) * 72 + jt * 16 + g * 4] = pk;
      }
      lst[it] += psum;
    }
    // order all waves' P-writes before PV-reads
    __syncthreads();
    #pragma unroll
    for (int ks = 0; ks < 2; ++ks) {
      short8 vf0 = *(const short8*)&VT[li * 264        + j0 + ks * 32 + g * 8];
      short8 vf1 = *(const short8*)&VT[(16 + li) * 264 + j0 + ks * 32 + g * 8];
      #pragma unroll
      for (int it = 0; it < 4; ++it) {
        short8 pf = *(const short8*)&Pw[(it * 16 + li) * 72 + ks * 32 + g * 8];
        oacc[0][it] = mfma16(vf0, pf, oacc[0][it]);
        oacc[1][it] = mfma16(vf1, pf, oacc[1][it]);
      }
    }
    // PV-reads complete before next chunk overwrites P
    __syncthreads();
  }
  #pragma unroll
  for (int it = 0; it < 4; ++it) {
    float lt = lst[it];
    lt += __shfl_xor(lt, 16);
    lt += __shfl_xor(lt, 32);
    float inv = 1.f / lt;
    int ic = w * 64 + it * 16 + li;
    #pragma unroll
    for (int ct = 0; ct < 2; ++ct) {
      int c0 = ct * 16 + g * 4;
      f32x4 gv = *(const f32x4*)(sgb + ((size_t)(base + ic)) * 32 + c0);
      ushort4 ov;
      ov.x = f2bf(oacc[ct][it][0] * inv * gv[0]);
      ov.y = f2bf(oacc[ct][it][1] * inv * gv[1]);
      ov.z = f2bf(oacc[ct][it][2] * inv * gv[2]);
      ov.w = f2bf(oacc[ct][it][3] * inv * gv[3]);
      *(ushort4*)&aob[((size_t)(ic * 256 + m)) * 128 + h * 32 + c0] = ov;
    }
  }
}

// ---------------- K4: output projection, bf16 MFMA ----------------
__global__ __launch_bounds__(256) void k_outg(const unsigned short* __restrict__ A,
                                              const unsigned short* __restrict__ Bt,
                                              const float* __restrict__ bo,
                                              float* __restrict__ out) {
  __shared__ unsigned short As[128 * 40];
  __shared__ unsigned short Bs[64 * 40];
  int t = threadIdx.x;
  int m0 = blockIdx.x * 128, n0 = blockIdx.y * 64;
  int w = t >> 6, l = t & 63, g = l >> 4, li = l & 15;
  int wr = w >> 1, wc = w & 1;
  f32x4 acc[4][2] = {};
  for (int s = 0; s < 4; ++s) {
    int k0 = s * 32;
    __syncthreads();
    {
      int row = t >> 1, kl = (t & 1) * 16;
      const short8* src = (const short8*)(A + (size_t)(m0 + row) * 128 + k0 + kl);
      *(short8*)&As[row * 40 + kl]     = src[0];
      *(short8*)&As[row * 40 + kl + 8] = src[1];
      int bn = t >> 2, bk = (t & 3) * 8;
      *(short8*)&Bs[bn * 40 + bk] = *(const short8*)(Bt + (size_t)(n0 + bn) * 128 + k0 + bk);
    }
    __syncthreads();
    short8 af[4], bf[2];
    #pragma unroll
    for (int it = 0; it < 4; ++it)
      af[it] = *(const short8*)&As[(wr * 64 + it * 16 + li) * 40 + g * 8];
    #pragma unroll
    for (int jt = 0; jt < 2; ++jt)
      bf[jt] = *(const short8*)&Bs[(wc * 32 + jt * 16 + li) * 40 + g * 8];
    #pragma unroll
    for (int it = 0; it < 4; ++it)
      #pragma unroll
      for (int jt = 0; jt < 2; ++jt)
        acc[it][jt] = mfma16(af[it], bf[jt], acc[it][jt]);
  }
  #pragma unroll
  for (int it = 0; it < 4; ++it)
    #pragma unroll
    for (int jt = 0; jt < 2; ++jt) {
      int n = n0 + wc * 32 + jt * 16 + li;
      float bias = bo[n];
      #pragma unroll
      for (int r = 0; r < 4; ++r) {
        int R = m0 + wr * 64 + it * 16 + g * 4 + r;
        out[(size_t)R * 128 + n] = acc[it][jt][r] + bias;
      }
    }
}

extern "C" void kernel_launch(void* const* d_in, const int* in_sizes, int n_in,
                              void* d_out, int out_size, void* d_ws, size_t ws_size,
                              hipStream_t stream) {
  const float* act  = (const float*)d_in[0];
  const float* mask = (const float*)d_in[1];
  const float* ln_g = (const float*)d_in[2];
  const float* ln_b = (const float*)d_in[3];
  const float* wq   = (const float*)d_in[4];
  const float* wk   = (const float*)d_in[5];
  const float* wv   = (const float*)d_in[6];
  const float* w2d  = (const float*)d_in[7];
  const float* wg   = (const float*)d_in[8];
  const float* bg   = (const float*)d_in[9];
  const float* wo   = (const float*)d_in[10];
  const float* bo   = (const float*)d_in[11];

  // Correct buffer sizes: q/k/v/g are [H*N*N rows = 262144][32 ch] = 8,388,608 elems each.
  char* p = (char*)d_ws;
  unsigned short* lnxb  = (unsigned short*)p;  p += (size_t)8388608 * 2;   // [65536][128] bf16
  float*          bias2 = (float*)p;           p += (size_t)262144 * 4;    // [4][65536] f32
  unsigned short* qb    = (unsigned short*)p;  p += (size_t)8388608 * 2;   // [262144][32] bf16
  unsigned short* kb    = (unsigned short*)p;  p += (size_t)8388608 * 2;
  unsigned short* vb    = (unsigned short*)p;  p += (size_t)8388608 * 2;
  float*          sgb   = (float*)p;           p += (size_t)8388608 * 4;   // [262144][32] f32
  unsigned short* aob   = (unsigned short*)p;  p += (size_t)8388608 * 2;   // [65536][128] bf16
  unsigned short* Wt4   = (unsigned short*)p;  p += (size_t)65536 * 2;
  unsigned short* Wto   = (unsigned short*)p;  p += (size_t)16384 * 2;
  float* out = (float*)d_out;

  hipLaunchKernelGGL(k_conv,  dim3(320),       dim3(256), 0, stream, wq, wk, wv, wg, wo, Wt4, Wto);
  hipLaunchKernelGGL(k_ln,    dim3(16384),     dim3(256), 0, stream, act, ln_g, ln_b, w2d, lnxb, bias2);
  hipLaunchKernelGGL(k_projg, dim3(512, 8),    dim3(256), 0, stream, lnxb, Wt4, bg, qb, kb, vb, sgb);
  hipLaunchKernelGGL(k_attn,  dim3(256, 4),    dim3(256), 0, stream, qb, kb, vb, sgb, bias2, mask, aob);
  hipLaunchKernelGGL(k_outg,  dim3(512, 2),    dim3(256), 0, stream, aob, Wto, bo, out);
}

// Round 5
// 132.870 us; speedup vs baseline: 3.1193x; 1.1840x over previous
//
#include <hip/hip_runtime.h>
#include <hip/hip_bf16.h>
#include <math.h>

// Shapes: B=1, N=256, C=128, H=4, CH=32
// d_in order: act, mask, ln_g, ln_b, wq, wk, wv, w2d, wg, bg, wo, bo (all fp32)

typedef __attribute__((ext_vector_type(8))) short short8;   // 8 bf16 (4 VGPRs)
typedef __attribute__((ext_vector_type(4))) short short4v;  // 4 bf16 (2 VGPRs)
typedef __attribute__((ext_vector_type(4))) float f32x4;

__device__ __forceinline__ unsigned short f2bf(float f) {
  __hip_bfloat16 b = __float2bfloat16(f);
  return __builtin_bit_cast(unsigned short, b);
}
__device__ __forceinline__ float bf2f(unsigned short u) {
  return __uint_as_float(((unsigned int)u) << 16);
}

__device__ __forceinline__ f32x4 mfma16(short8 a, short8 b, f32x4 c) {
  return __builtin_amdgcn_mfma_f32_16x16x32_bf16(a, b, c, 0, 0, 0);
}

__device__ __forceinline__ float wave_reduce_sum(float v) {
  #pragma unroll
  for (int off = 32; off; off >>= 1) v += __shfl_xor(v, off, 64);
  return v;
}

// ---------------- K0: convert weights to bf16, transposed ----------------
__global__ __launch_bounds__(256) void k_conv(const float* __restrict__ wq,
                                              const float* __restrict__ wk,
                                              const float* __restrict__ wv,
                                              const float* __restrict__ wg,
                                              const float* __restrict__ wo,
                                              unsigned short* __restrict__ Wt4,
                                              unsigned short* __restrict__ Wto) {
  int idx = blockIdx.x * 256 + threadIdx.x;
  if (idx < 65536) {
    int n = idx >> 7, k = idx & 127;
    const float* ws = (n < 128) ? wq : (n < 256) ? wk : (n < 384) ? wv : wg;
    Wt4[idx] = f2bf(ws[k * 128 + (n & 127)]);
  } else if (idx < 81920) {
    int j = idx - 65536;
    int n = j >> 7, k = j & 127;
    Wto[j] = f2bf(wo[k * 128 + n]);
  }
}

// ---------------- K1: LayerNorm (axis-swapped) + pair-bias dot ----------------
// lnxb[mm*256+ii][c]; b2t[h][ii*256+mm] = dot (transposed so attention's
// S^T-layout bias reads are lane-contiguous)
__global__ __launch_bounds__(256) void k_ln(const float* __restrict__ act,
                                            const float* __restrict__ ln_g,
                                            const float* __restrict__ ln_b,
                                            const float* __restrict__ w2d,
                                            unsigned short* __restrict__ lnxb,
                                            float* __restrict__ b2t) {
  int row  = blockIdx.x * 4 + (threadIdx.x >> 6);
  int lane = threadIdx.x & 63;
  int mm = row >> 8, ii = row & 255;
  const float* a = act + ((size_t)(ii * 256 + mm)) * 128;
  float a0 = a[lane], a1 = a[lane + 64];
  float sum = wave_reduce_sum(a0 + a1);
  float mean = sum * (1.f / 128.f);
  float e0 = a0 - mean, e1 = a1 - mean;
  float var = wave_reduce_sum(e0 * e0 + e1 * e1) * (1.f / 128.f);
  float rstd = rsqrtf(var + 1e-5f);
  float y0 = e0 * rstd * ln_g[lane]      + ln_b[lane];
  float y1 = e1 * rstd * ln_g[lane + 64] + ln_b[lane + 64];
  unsigned short* o = lnxb + (size_t)row * 128;
  o[lane]      = f2bf(y0);
  o[lane + 64] = f2bf(y1);
  #pragma unroll
  for (int h = 0; h < 4; ++h) {
    float b = y0 * w2d[lane * 4 + h] + y1 * w2d[(lane + 64) * 4 + h];
    b = wave_reduce_sum(b);
    if (lane == 0) b2t[h * 65536 + ii * 256 + mm] = b;   // transposed store
  }
}

// ---------------- K2: fused q/k/v/g projection, bf16 MFMA ----------------
__global__ __launch_bounds__(256) void k_projg(const unsigned short* __restrict__ A,
                                               const unsigned short* __restrict__ Bt,
                                               const float* __restrict__ bg,
                                               unsigned short* __restrict__ qb,
                                               unsigned short* __restrict__ kb,
                                               unsigned short* __restrict__ vb,
                                               unsigned short* __restrict__ sgb) {
  __shared__ unsigned short As[128 * 40];
  __shared__ unsigned short Bs[64 * 40];
  int t = threadIdx.x;
  int m0 = blockIdx.x * 128, n0 = blockIdx.y * 64;
  int w = t >> 6, l = t & 63, g = l >> 4, li = l & 15;
  int wr = w >> 1, wc = w & 1;
  f32x4 acc[4][2] = {};
  for (int s = 0; s < 4; ++s) {
    int k0 = s * 32;
    __syncthreads();
    {
      int row = t >> 1, kl = (t & 1) * 16;
      const short8* src = (const short8*)(A + (size_t)(m0 + row) * 128 + k0 + kl);
      *(short8*)&As[row * 40 + kl]     = src[0];
      *(short8*)&As[row * 40 + kl + 8] = src[1];
      int bn = t >> 2, bk = (t & 3) * 8;
      *(short8*)&Bs[bn * 40 + bk] = *(const short8*)(Bt + (size_t)(n0 + bn) * 128 + k0 + bk);
    }
    __syncthreads();
    short8 af[4], bf[2];
    #pragma unroll
    for (int it = 0; it < 4; ++it)
      af[it] = *(const short8*)&As[(wr * 64 + it * 16 + li) * 40 + g * 8];
    #pragma unroll
    for (int jt = 0; jt < 2; ++jt)
      bf[jt] = *(const short8*)&Bs[(wc * 32 + jt * 16 + li) * 40 + g * 8];
    #pragma unroll
    for (int it = 0; it < 4; ++it)
      #pragma unroll
      for (int jt = 0; jt < 2; ++jt)
        acc[it][jt] = mfma16(af[it], bf[jt], acc[it][jt]);
  }
  int which = n0 >> 7;
  const float factor = 0.17677669529663687f;  // 1/sqrt(32)
  #pragma unroll
  for (int it = 0; it < 4; ++it)
    #pragma unroll
    for (int jt = 0; jt < 2; ++jt) {
      int n = n0 + wc * 32 + jt * 16 + li;
      int hh = (n >> 5) & 3, ch = n & 31;
      #pragma unroll
      for (int r = 0; r < 4; ++r) {
        int R = m0 + wr * 64 + it * 16 + g * 4 + r;
        int mm = R >> 8, ii = R & 255;
        size_t o = ((size_t)((mm * 4 + hh) * 256 + ii)) * 32 + ch;
        float v = acc[it][jt][r];
        if (which == 0)      qb[o] = f2bf(v * factor);
        else if (which == 1) kb[o] = f2bf(v);
        else if (which == 2) vb[o] = f2bf(v);
        else                 sgb[o] = f2bf(1.f / (1.f + __expf(-(v + bg[n & 127]))));
      }
    }
}

// ---------------- K3: attention, MFMA flash-style ----------------
// grid (m, h, ihalf); block 256 = 4 waves; wave handles 32 i-rows.
__global__ __launch_bounds__(256) void k_attn(const unsigned short* __restrict__ qb,
                                              const unsigned short* __restrict__ kb,
                                              const unsigned short* __restrict__ vb,
                                              const unsigned short* __restrict__ sgb,
                                              const float* __restrict__ b2t,
                                              const float* __restrict__ mask,
                                              unsigned short* __restrict__ aob) {
  __shared__ unsigned short VT[32 * 264];    // V^T [c][j], pad 264 (528B stride)
  __shared__ unsigned short Pl[4 * 32 * 72]; // per-wave P [i][j], pad 72 (144B)
  __shared__ float maskls[256];
  int m = blockIdx.x, h = blockIdx.y, ihalf = blockIdx.z;
  int t = threadIdx.x, w = t >> 6, l = t & 63, g = l >> 4, li = l & 15;
  int base = (m * 4 + h) << 8;
  maskls[t] = 1e9f * (mask[t * 256 + m] - 1.0f);
  {  // stage V^T
    const unsigned int* v32 = (const unsigned int*)(vb + (size_t)base * 32);
    #pragma unroll
    for (int p = 0; p < 16; ++p) {
      int idx = t + p * 256;
      int j = idx >> 4, cp = idx & 15;
      unsigned int u = v32[idx];
      VT[(cp * 2) * 264 + j]     = (unsigned short)(u & 0xffff);
      VT[(cp * 2 + 1) * 264 + j] = (unsigned short)(u >> 16);
    }
  }
  __syncthreads();
  int i0 = ihalf * 128 + w * 32;
  short8 qf[2];
  #pragma unroll
  for (int it = 0; it < 2; ++it)
    qf[it] = *(const short8*)(qb + ((size_t)(base + i0 + it * 16 + li)) * 32 + g * 8);
  float mst[2] = {-1e30f, -1e30f};
  float lst[2] = {0.f, 0.f};
  f32x4 oacc[2][2] = {};
  const float* b2 = b2t + (size_t)h * 65536;
  unsigned short* Pw = Pl + w * 32 * 72;
  for (int jc = 0; jc < 4; ++jc) {
    int j0 = jc * 64;
    f32x4 sacc[4][2];
    #pragma unroll
    for (int jt = 0; jt < 4; ++jt) {
      short8 kf = *(const short8*)(kb + ((size_t)(base + j0 + jt * 16 + li)) * 32 + g * 8);
      #pragma unroll
      for (int it = 0; it < 2; ++it) {
        f32x4 z = {0.f, 0.f, 0.f, 0.f};
        sacc[jt][it] = mfma16(kf, qf[it], z);
      }
    }
    #pragma unroll
    for (int it = 0; it < 2; ++it) {
      int ic = i0 + it * 16 + li;
      float s[16];
      float cmax = -1e30f;
      #pragma unroll
      for (int jt = 0; jt < 4; ++jt) {
        int jb = j0 + jt * 16 + g * 4;
        f32x4 mk = *(const f32x4*)&maskls[jb];
        #pragma unroll
        for (int r = 0; r < 4; ++r) {
          // b2t[j][i]: lane-contiguous (i = ic varies with li)
          float sv = sacc[jt][it][r] + b2[(size_t)(jb + r) * 256 + ic] + mk[r];
          s[jt * 4 + r] = sv;
          cmax = fmaxf(cmax, sv);
        }
      }
      cmax = fmaxf(cmax, __shfl_xor(cmax, 16));
      cmax = fmaxf(cmax, __shfl_xor(cmax, 32));
      float mnew = fmaxf(mst[it], cmax);
      float fac = __expf(mst[it] - mnew);
      mst[it] = mnew;
      lst[it] *= fac;
      oacc[0][it] *= fac;
      oacc[1][it] *= fac;
      float psum = 0.f;
      #pragma unroll
      for (int jt = 0; jt < 4; ++jt) {
        float p0 = __expf(s[jt * 4 + 0] - mnew);
        float p1 = __expf(s[jt * 4 + 1] - mnew);
        float p2 = __expf(s[jt * 4 + 2] - mnew);
        float p3 = __expf(s[jt * 4 + 3] - mnew);
        psum += p0 + p1 + p2 + p3;
        short4v pk;
        pk.x = (short)f2bf(p0); pk.y = (short)f2bf(p1);
        pk.z = (short)f2bf(p2); pk.w = (short)f2bf(p3);
        *(short4v*)&Pw[(it * 16 + li) * 72 + jt * 16 + g * 4] = pk;
      }
      lst[it] += psum;
    }
    // P is per-wave private: no barrier needed. Compiler fence orders the
    // ds_writes above before the ds_reads below (HW DS ops are in-order per wave).
    asm volatile("" ::: "memory");
    #pragma unroll
    for (int ks = 0; ks < 2; ++ks) {
      short8 vf0 = *(const short8*)&VT[li * 264        + j0 + ks * 32 + g * 8];
      short8 vf1 = *(const short8*)&VT[(16 + li) * 264 + j0 + ks * 32 + g * 8];
      #pragma unroll
      for (int it = 0; it < 2; ++it) {
        short8 pf = *(const short8*)&Pw[(it * 16 + li) * 72 + ks * 32 + g * 8];
        oacc[0][it] = mfma16(vf0, pf, oacc[0][it]);
        oacc[1][it] = mfma16(vf1, pf, oacc[1][it]);
      }
    }
    asm volatile("" ::: "memory");  // PV reads complete before next chunk's writes
  }
  #pragma unroll
  for (int it = 0; it < 2; ++it) {
    float lt = lst[it];
    lt += __shfl_xor(lt, 16);
    lt += __shfl_xor(lt, 32);
    float inv = 1.f / lt;
    int ic = i0 + it * 16 + li;
    #pragma unroll
    for (int ct = 0; ct < 2; ++ct) {
      int c0 = ct * 16 + g * 4;
      const unsigned short* grow = sgb + ((size_t)(base + ic)) * 32 + c0;
      ushort4 gu = *(const ushort4*)grow;
      ushort4 ov;
      ov.x = f2bf(oacc[ct][it][0] * inv * bf2f(gu.x));
      ov.y = f2bf(oacc[ct][it][1] * inv * bf2f(gu.y));
      ov.z = f2bf(oacc[ct][it][2] * inv * bf2f(gu.z));
      ov.w = f2bf(oacc[ct][it][3] * inv * bf2f(gu.w));
      *(ushort4*)&aob[((size_t)(ic * 256 + m)) * 128 + h * 32 + c0] = ov;
    }
  }
}

// ---------------- K4: output projection, bf16 MFMA ----------------
__global__ __launch_bounds__(256) void k_outg(const unsigned short* __restrict__ A,
                                              const unsigned short* __restrict__ Bt,
                                              const float* __restrict__ bo,
                                              float* __restrict__ out) {
  __shared__ unsigned short As[128 * 40];
  __shared__ unsigned short Bs[64 * 40];
  int t = threadIdx.x;
  int m0 = blockIdx.x * 128, n0 = blockIdx.y * 64;
  int w = t >> 6, l = t & 63, g = l >> 4, li = l & 15;
  int wr = w >> 1, wc = w & 1;
  f32x4 acc[4][2] = {};
  for (int s = 0; s < 4; ++s) {
    int k0 = s * 32;
    __syncthreads();
    {
      int row = t >> 1, kl = (t & 1) * 16;
      const short8* src = (const short8*)(A + (size_t)(m0 + row) * 128 + k0 + kl);
      *(short8*)&As[row * 40 + kl]     = src[0];
      *(short8*)&As[row * 40 + kl + 8] = src[1];
      int bn = t >> 2, bk = (t & 3) * 8;
      *(short8*)&Bs[bn * 40 + bk] = *(const short8*)(Bt + (size_t)(n0 + bn) * 128 + k0 + bk);
    }
    __syncthreads();
    short8 af[4], bf[2];
    #pragma unroll
    for (int it = 0; it < 4; ++it)
      af[it] = *(const short8*)&As[(wr * 64 + it * 16 + li) * 40 + g * 8];
    #pragma unroll
    for (int jt = 0; jt < 2; ++jt)
      bf[jt] = *(const short8*)&Bs[(wc * 32 + jt * 16 + li) * 40 + g * 8];
    #pragma unroll
    for (int it = 0; it < 4; ++it)
      #pragma unroll
      for (int jt = 0; jt < 2; ++jt)
        acc[it][jt] = mfma16(af[it], bf[jt], acc[it][jt]);
  }
  #pragma unroll
  for (int it = 0; it < 4; ++it)
    #pragma unroll
    for (int jt = 0; jt < 2; ++jt) {
      int n = n0 + wc * 32 + jt * 16 + li;
      float bias = bo[n];
      #pragma unroll
      for (int r = 0; r < 4; ++r) {
        int R = m0 + wr * 64 + it * 16 + g * 4 + r;
        out[(size_t)R * 128 + n] = acc[it][jt][r] + bias;
      }
    }
}

extern "C" void kernel_launch(void* const* d_in, const int* in_sizes, int n_in,
                              void* d_out, int out_size, void* d_ws, size_t ws_size,
                              hipStream_t stream) {
  const float* act  = (const float*)d_in[0];
  const float* mask = (const float*)d_in[1];
  const float* ln_g = (const float*)d_in[2];
  const float* ln_b = (const float*)d_in[3];
  const float* wq   = (const float*)d_in[4];
  const float* wk   = (const float*)d_in[5];
  const float* wv   = (const float*)d_in[6];
  const float* w2d  = (const float*)d_in[7];
  const float* wg   = (const float*)d_in[8];
  const float* bg   = (const float*)d_in[9];
  const float* wo   = (const float*)d_in[10];
  const float* bo   = (const float*)d_in[11];

  char* p = (char*)d_ws;
  unsigned short* lnxb  = (unsigned short*)p;  p += (size_t)8388608 * 2;   // [65536][128] bf16
  float*          b2t   = (float*)p;           p += (size_t)262144 * 4;    // [4][j*256+i] f32
  unsigned short* qb    = (unsigned short*)p;  p += (size_t)8388608 * 2;   // [262144][32] bf16
  unsigned short* kb    = (unsigned short*)p;  p += (size_t)8388608 * 2;
  unsigned short* vb    = (unsigned short*)p;  p += (size_t)8388608 * 2;
  unsigned short* sgb   = (unsigned short*)p;  p += (size_t)8388608 * 2;   // gate, bf16
  unsigned short* aob   = (unsigned short*)p;  p += (size_t)8388608 * 2;   // [65536][128] bf16
  unsigned short* Wt4   = (unsigned short*)p;  p += (size_t)65536 * 2;
  unsigned short* Wto   = (unsigned short*)p;  p += (size_t)16384 * 2;
  float* out = (float*)d_out;

  hipLaunchKernelGGL(k_conv,  dim3(320),        dim3(256), 0, stream, wq, wk, wv, wg, wo, Wt4, Wto);
  hipLaunchKernelGGL(k_ln,    dim3(16384),      dim3(256), 0, stream, act, ln_g, ln_b, w2d, lnxb, b2t);
  hipLaunchKernelGGL(k_projg, dim3(512, 8),     dim3(256), 0, stream, lnxb, Wt4, bg, qb, kb, vb, sgb);
  hipLaunchKernelGGL(k_attn,  dim3(256, 4, 2),  dim3(256), 0, stream, qb, kb, vb, sgb, b2t, mask, aob);
  hipLaunchKernelGGL(k_outg,  dim3(512, 2),     dim3(256), 0, stream, aob, Wto, bo, out);
}